// Round 1
// baseline (1228.287 us; speedup 1.0000x reference)
//
#include <hip/hip_runtime.h>

#define N_NODES 50000
#define N_EDGES 800000
#define IN_F 128
#define HID 96
#define NCLS 21

// ---------------- degree / dinv ----------------
__global__ void k_deg_init(float* __restrict__ deg) {
  int i = blockIdx.x * blockDim.x + threadIdx.x;
  if (i < N_NODES) deg[i] = 1.0f;  // self-loop
}

__global__ void k_deg_count(const int* __restrict__ tgt, float* __restrict__ deg) {
  int e = blockIdx.x * blockDim.x + threadIdx.x;
  if (e < N_EDGES) atomicAdd(&deg[tgt[e]], 1.0f);  // exact integer sums in f32
}

__global__ void k_dinv(float* __restrict__ d) {
  int i = blockIdx.x * blockDim.x + threadIdx.x;
  if (i < N_NODES) d[i] = rsqrtf(d[i]);
}

// ---------------- dense transform: g[n][f] = dinv[n] * sum_k A[n][k] W[k][f] ----------------
template<int K>
__global__ __launch_bounds__(384) void k_gemm_scale(
    const float* __restrict__ A, const float* __restrict__ W,
    const float* __restrict__ dinv, float* __restrict__ g) {
  __shared__ float w[K][HID];
  int f = threadIdx.x;   // 0..95
  int ty = threadIdx.y;  // 0..3
  int tid = ty * HID + f;
  for (int i = tid; i < K * HID; i += 384) w[i / HID][i % HID] = W[i];
  __syncthreads();
  int n = blockIdx.x * 4 + ty;
  if (n >= N_NODES) return;
  const float* a = A + (size_t)n * K;
  float s = 0.f;
#pragma unroll
  for (int k = 0; k < K; k += 4) {
    float4 a4 = *reinterpret_cast<const float4*>(a + k);
    s += a4.x * w[k][f];
    s += a4.y * w[k + 1][f];
    s += a4.z * w[k + 2][f];
    s += a4.w * w[k + 3][f];
  }
  g[(size_t)n * HID + f] = s * dinv[n];
}

// ---------------- init agg = g (self-loop term) ----------------
__global__ void k_copy4(const float4* __restrict__ s, float4* __restrict__ d, int n4) {
  int i = blockIdx.x * blockDim.x + threadIdx.x;
  if (i < n4) d[i] = s[i];
}

// ---------------- edge scatter: agg[tgt] += g[src] ----------------
__global__ __launch_bounds__(256) void k_scatter(
    const int* __restrict__ src, const int* __restrict__ tgt,
    const float* __restrict__ g, float* __restrict__ agg) {
  unsigned idx = blockIdx.x * 256u + threadIdx.x;
  if (idx >= (unsigned)N_EDGES * HID) return;
  unsigned e = idx / HID;
  unsigned f = idx - e * HID;
  int s = src[e];
  int t = tgt[e];
  atomicAdd(&agg[(size_t)t * HID + f], g[(size_t)s * HID + f]);
}

// ---------------- epilogue: h = leaky(dinv*agg + b), in place ----------------
__global__ void k_post(float* __restrict__ h, const float* __restrict__ dinv,
                       const float* __restrict__ b) {
  int idx = blockIdx.x * blockDim.x + threadIdx.x;
  if (idx >= N_NODES * HID) return;
  int n = idx / HID;
  int f = idx - n * HID;
  float v = dinv[n] * h[idx] + b[f];
  h[idx] = v > 0.f ? v : 0.01f * v;
}

// ---------------- final linear: out = H @ Wl + bl ----------------
__global__ __launch_bounds__(256) void k_final(
    const float* __restrict__ H, const float* __restrict__ Wl,
    const float* __restrict__ bl, float* __restrict__ out) {
  __shared__ float w[HID * NCLS];
  __shared__ float bs[NCLS];
  int tid = threadIdx.x;
  for (int i = tid; i < HID * NCLS; i += 256) w[i] = Wl[i];
  if (tid < NCLS) bs[tid] = bl[tid];
  __syncthreads();
  int idx = blockIdx.x * 256 + tid;
  if (idx >= N_NODES * NCLS) return;
  int n = idx / NCLS;
  int c = idx - n * NCLS;
  const float* a = H + (size_t)n * HID;
  float s = bs[c];
#pragma unroll
  for (int k = 0; k < HID; k++) s += a[k] * w[k * NCLS + c];
  out[idx] = s;
}

extern "C" void kernel_launch(void* const* d_in, const int* in_sizes, int n_in,
                              void* d_out, int out_size, void* d_ws, size_t ws_size,
                              hipStream_t stream) {
  const float* x  = (const float*)d_in[0];
  const int* ei   = (const int*)d_in[1];
  const int* src  = ei;             // edge_index[0]
  const int* tgt  = ei + N_EDGES;   // edge_index[1]
  const float* W1 = (const float*)d_in[2];
  const float* b1 = (const float*)d_in[3];
  const float* W2 = (const float*)d_in[4];
  const float* b2 = (const float*)d_in[5];
  const float* W3 = (const float*)d_in[6];
  const float* b3 = (const float*)d_in[7];
  const float* Wl = (const float*)d_in[8];
  const float* bl = (const float*)d_in[9];
  float* out = (float*)d_out;

  float* dinv = (float*)d_ws;                       // N floats
  float* bufA = dinv + N_NODES;                     // g      [N,96]
  float* bufB = bufA + (size_t)N_NODES * HID;       // agg/h  [N,96]

  // degree -> dinv (reused by all layers)
  k_deg_init<<<(N_NODES + 255) / 256, 256, 0, stream>>>(dinv);
  k_deg_count<<<(N_EDGES + 255) / 256, 256, 0, stream>>>(tgt, dinv);
  k_dinv<<<(N_NODES + 255) / 256, 256, 0, stream>>>(dinv);

  dim3 gblk(HID, 4);
  int ggrid = (N_NODES + 3) / 4;
  const int NF = N_NODES * HID;
  const unsigned EF = (unsigned)N_EDGES * HID;
  const int n4 = NF / 4;

  // ---- layer 1 ----
  k_gemm_scale<IN_F><<<ggrid, gblk, 0, stream>>>(x, W1, dinv, bufA);
  k_copy4<<<(n4 + 255) / 256, 256, 0, stream>>>((const float4*)bufA, (float4*)bufB, n4);
  k_scatter<<<(EF + 255u) / 256u, 256, 0, stream>>>(src, tgt, bufA, bufB);
  k_post<<<(NF + 255) / 256, 256, 0, stream>>>(bufB, dinv, b1);

  // ---- layer 2 ----
  k_gemm_scale<HID><<<ggrid, gblk, 0, stream>>>(bufB, W2, dinv, bufA);
  k_copy4<<<(n4 + 255) / 256, 256, 0, stream>>>((const float4*)bufA, (float4*)bufB, n4);
  k_scatter<<<(EF + 255u) / 256u, 256, 0, stream>>>(src, tgt, bufA, bufB);
  k_post<<<(NF + 255) / 256, 256, 0, stream>>>(bufB, dinv, b2);

  // ---- layer 3 ----
  k_gemm_scale<HID><<<ggrid, gblk, 0, stream>>>(bufB, W3, dinv, bufA);
  k_copy4<<<(n4 + 255) / 256, 256, 0, stream>>>((const float4*)bufA, (float4*)bufB, n4);
  k_scatter<<<(EF + 255u) / 256u, 256, 0, stream>>>(src, tgt, bufA, bufB);
  k_post<<<(NF + 255) / 256, 256, 0, stream>>>(bufB, dinv, b3);

  // ---- classifier ----
  k_final<<<(N_NODES * NCLS + 255) / 256, 256, 0, stream>>>(bufB, Wl, bl, out);
}

// Round 2
// 766.953 us; speedup vs baseline: 1.6015x; 1.6015x over previous
//
#include <hip/hip_runtime.h>

#define N_NODES 50000
#define N_EDGES 800000
#define IN_F 128
#define HID 96
#define NCLS 21

// ---------------- CSR build ----------------
__global__ void k_zero_int(int* __restrict__ p, int n) {
  int i = blockIdx.x * blockDim.x + threadIdx.x;
  if (i < n) p[i] = 0;
}

__global__ void k_hist(const int* __restrict__ tgt, int* __restrict__ cnt) {
  int e = blockIdx.x * blockDim.x + threadIdx.x;
  if (e < N_EDGES) atomicAdd(&cnt[tgt[e]], 1);
}

// exclusive scan of cnt[0..N) -> rowptr[0..N], single 1024-thread block
__global__ __launch_bounds__(1024) void k_scan(const int* __restrict__ cnt,
                                               int* __restrict__ rowptr) {
  __shared__ int wsum[16];
  __shared__ int base_sh;
  int tid = threadIdx.x;
  int lane = tid & 63, wid = tid >> 6;
  if (tid == 0) base_sh = 0;
  __syncthreads();
  for (int base = 0; base < N_NODES; base += 1024) {
    int i = base + tid;
    int v = (i < N_NODES) ? cnt[i] : 0;
    int x = v;
#pragma unroll
    for (int off = 1; off < 64; off <<= 1) {
      int y = __shfl_up(x, off);
      if (lane >= off) x += y;
    }
    if (lane == 63) wsum[wid] = x;
    __syncthreads();
    if (tid < 16) {
      int w = wsum[tid];
#pragma unroll
      for (int off = 1; off < 16; off <<= 1) {
        int y = __shfl_up(w, off);
        if (tid >= off) w += y;
      }
      wsum[tid] = w;
    }
    __syncthreads();
    int chunk_base = base_sh;
    int excl = chunk_base + (wid ? wsum[wid - 1] : 0) + x - v;
    if (i < N_NODES) rowptr[i] = excl;
    __syncthreads();
    if (tid == 0) base_sh += wsum[15];
    __syncthreads();
  }
  if (tid == 0) rowptr[N_NODES] = base_sh;
}

__global__ void k_dinv_from_cnt(const int* __restrict__ cnt, float* __restrict__ dinv) {
  int i = blockIdx.x * blockDim.x + threadIdx.x;
  if (i < N_NODES) dinv[i] = rsqrtf(1.0f + (float)cnt[i]);  // +1 self-loop
}

__global__ void k_copy_int(const int* __restrict__ s, int* __restrict__ d, int n) {
  int i = blockIdx.x * blockDim.x + threadIdx.x;
  if (i < n) d[i] = s[i];
}

__global__ void k_fill(const int* __restrict__ src, const int* __restrict__ tgt,
                       int* __restrict__ cursor, int* __restrict__ adj) {
  int e = blockIdx.x * blockDim.x + threadIdx.x;
  if (e < N_EDGES) {
    int pos = atomicAdd(&cursor[tgt[e]], 1);
    adj[pos] = src[e];
  }
}

// ---------------- dense transform: g[n][f] = dinv[n] * sum_k A[n][k] W[k][f] ----------------
template<int K>
__global__ __launch_bounds__(384) void k_gemm_scale(
    const float* __restrict__ A, const float* __restrict__ W,
    const float* __restrict__ dinv, float* __restrict__ g) {
  __shared__ float w[K][HID];
  int f = threadIdx.x;   // 0..95
  int ty = threadIdx.y;  // 0..3
  int tid = ty * HID + f;
  for (int i = tid; i < K * HID; i += 384) w[i / HID][i % HID] = W[i];
  __syncthreads();
  int n = blockIdx.x * 4 + ty;
  if (n >= N_NODES) return;
  const float* a = A + (size_t)n * K;
  float s = 0.f;
#pragma unroll
  for (int k = 0; k < K; k += 4) {
    float4 a4 = *reinterpret_cast<const float4*>(a + k);
    s += a4.x * w[k][f];
    s += a4.y * w[k + 1][f];
    s += a4.z * w[k + 2][f];
    s += a4.w * w[k + 3][f];
  }
  g[(size_t)n * HID + f] = s * dinv[n];
}

// ---------------- fused aggregate: h = leaky(dinv*(g[n] + sum_in g[src]) + b) ----------------
// one wave per node; lane covers feature f (and f+64 for lane<32)
__global__ __launch_bounds__(256) void k_aggregate(
    const float* __restrict__ g, const int* __restrict__ rowptr,
    const int* __restrict__ adj, const float* __restrict__ dinv,
    const float* __restrict__ b, float* __restrict__ h) {
  int wave = threadIdx.x >> 6;
  int lane = threadIdx.x & 63;
  int n = blockIdx.x * 4 + wave;
  if (n >= N_NODES) return;
  const float* grow = g + (size_t)n * HID;
  float s0 = grow[lane];
  float s1 = (lane < 32) ? grow[64 + lane] : 0.f;
  int beg = rowptr[n], end = rowptr[n + 1];
  for (int e = beg; e < end; e++) {
    int src = adj[e];
    const float* gs = g + (size_t)src * HID;
    s0 += gs[lane];
    if (lane < 32) s1 += gs[64 + lane];
  }
  float d = dinv[n];
  float v0 = d * s0 + b[lane];
  h[(size_t)n * HID + lane] = v0 > 0.f ? v0 : 0.01f * v0;
  if (lane < 32) {
    float v1 = d * s1 + b[64 + lane];
    h[(size_t)n * HID + 64 + lane] = v1 > 0.f ? v1 : 0.01f * v1;
  }
}

// ---------------- final linear: out = H @ Wl + bl ----------------
__global__ __launch_bounds__(256) void k_final(
    const float* __restrict__ H, const float* __restrict__ Wl,
    const float* __restrict__ bl, float* __restrict__ out) {
  __shared__ float w[HID * NCLS];
  __shared__ float bs[NCLS];
  int tid = threadIdx.x;
  for (int i = tid; i < HID * NCLS; i += 256) w[i] = Wl[i];
  if (tid < NCLS) bs[tid] = bl[tid];
  __syncthreads();
  int idx = blockIdx.x * 256 + tid;
  if (idx >= N_NODES * NCLS) return;
  int n = idx / NCLS;
  int c = idx - n * NCLS;
  const float* a = H + (size_t)n * HID;
  float s = bs[c];
#pragma unroll
  for (int k = 0; k < HID; k++) s += a[k] * w[k * NCLS + c];
  out[idx] = s;
}

extern "C" void kernel_launch(void* const* d_in, const int* in_sizes, int n_in,
                              void* d_out, int out_size, void* d_ws, size_t ws_size,
                              hipStream_t stream) {
  const float* x  = (const float*)d_in[0];
  const int* ei   = (const int*)d_in[1];
  const int* src  = ei;             // edge_index[0]
  const int* tgt  = ei + N_EDGES;   // edge_index[1]
  const float* W1 = (const float*)d_in[2];
  const float* b1 = (const float*)d_in[3];
  const float* W2 = (const float*)d_in[4];
  const float* b2 = (const float*)d_in[5];
  const float* W3 = (const float*)d_in[6];
  const float* b3 = (const float*)d_in[7];
  const float* Wl = (const float*)d_in[8];
  const float* bl = (const float*)d_in[9];
  float* out = (float*)d_out;

  // workspace layout
  float* dinv   = (float*)d_ws;                       // N
  float* bufA   = dinv + N_NODES;                     // N*96
  float* bufB   = bufA + (size_t)N_NODES * HID;       // N*96
  int*   cnt    = (int*)(bufB + (size_t)N_NODES * HID);  // N
  int*   rowptr = cnt + N_NODES;                      // N+1
  int*   cursor = rowptr + N_NODES + 1;               // N
  int*   adj    = cursor + N_NODES;                   // E

  // ---- CSR build (also yields degrees -> dinv) ----
  k_zero_int<<<(N_NODES + 255) / 256, 256, 0, stream>>>(cnt, N_NODES);
  k_hist<<<(N_EDGES + 255) / 256, 256, 0, stream>>>(tgt, cnt);
  k_scan<<<1, 1024, 0, stream>>>(cnt, rowptr);
  k_dinv_from_cnt<<<(N_NODES + 255) / 256, 256, 0, stream>>>(cnt, dinv);
  k_copy_int<<<(N_NODES + 255) / 256, 256, 0, stream>>>(rowptr, cursor, N_NODES);
  k_fill<<<(N_EDGES + 255) / 256, 256, 0, stream>>>(src, tgt, cursor, adj);

  dim3 gblk(HID, 4);
  int ggrid = (N_NODES + 3) / 4;
  int agrid = (N_NODES + 3) / 4;

  // ---- layer 1 ----
  k_gemm_scale<IN_F><<<ggrid, gblk, 0, stream>>>(x, W1, dinv, bufA);
  k_aggregate<<<agrid, 256, 0, stream>>>(bufA, rowptr, adj, dinv, b1, bufB);
  // ---- layer 2 ----
  k_gemm_scale<HID><<<ggrid, gblk, 0, stream>>>(bufB, W2, dinv, bufA);
  k_aggregate<<<agrid, 256, 0, stream>>>(bufA, rowptr, adj, dinv, b2, bufB);
  // ---- layer 3 ----
  k_gemm_scale<HID><<<ggrid, gblk, 0, stream>>>(bufB, W3, dinv, bufA);
  k_aggregate<<<agrid, 256, 0, stream>>>(bufA, rowptr, adj, dinv, b3, bufB);

  // ---- classifier ----
  k_final<<<(N_NODES * NCLS + 255) / 256, 256, 0, stream>>>(bufB, Wl, bl, out);
}

// Round 3
// 499.583 us; speedup vs baseline: 2.4586x; 1.5352x over previous
//
#include <hip/hip_runtime.h>

#define N_NODES 50000
#define N_EDGES 800000
#define IN_F 128
#define HID 96
#define NCLS 21

// ---------------- CSR build ----------------
__global__ void k_zero_int(int* __restrict__ p, int n) {
  int i = blockIdx.x * blockDim.x + threadIdx.x;
  if (i < n) p[i] = 0;
}

__global__ void k_hist(const int* __restrict__ tgt, int* __restrict__ cnt) {
  int e = blockIdx.x * blockDim.x + threadIdx.x;
  if (e < N_EDGES) atomicAdd(&cnt[tgt[e]], 1);
}

// exclusive scan of cnt[0..N) -> rowptr[0..N], single 1024-thread block
__global__ __launch_bounds__(1024) void k_scan(const int* __restrict__ cnt,
                                               int* __restrict__ rowptr) {
  __shared__ int wsum[16];
  __shared__ int base_sh;
  int tid = threadIdx.x;
  int lane = tid & 63, wid = tid >> 6;
  if (tid == 0) base_sh = 0;
  __syncthreads();
  for (int base = 0; base < N_NODES; base += 1024) {
    int i = base + tid;
    int v = (i < N_NODES) ? cnt[i] : 0;
    int x = v;
#pragma unroll
    for (int off = 1; off < 64; off <<= 1) {
      int y = __shfl_up(x, off);
      if (lane >= off) x += y;
    }
    if (lane == 63) wsum[wid] = x;
    __syncthreads();
    if (tid < 16) {
      int w = wsum[tid];
#pragma unroll
      for (int off = 1; off < 16; off <<= 1) {
        int y = __shfl_up(w, off);
        if (tid >= off) w += y;
      }
      wsum[tid] = w;
    }
    __syncthreads();
    int chunk_base = base_sh;
    int excl = chunk_base + (wid ? wsum[wid - 1] : 0) + x - v;
    if (i < N_NODES) rowptr[i] = excl;
    __syncthreads();
    if (tid == 0) base_sh += wsum[15];
    __syncthreads();
  }
  if (tid == 0) rowptr[N_NODES] = base_sh;
}

__global__ void k_dinv_from_cnt(const int* __restrict__ cnt, float* __restrict__ dinv) {
  int i = blockIdx.x * blockDim.x + threadIdx.x;
  if (i < N_NODES) dinv[i] = rsqrtf(1.0f + (float)cnt[i]);  // +1 self-loop
}

__global__ void k_copy_int(const int* __restrict__ s, int* __restrict__ d, int n) {
  int i = blockIdx.x * blockDim.x + threadIdx.x;
  if (i < n) d[i] = s[i];
}

__global__ void k_fill(const int* __restrict__ src, const int* __restrict__ tgt,
                       int* __restrict__ cursor, int* __restrict__ adj) {
  int e = blockIdx.x * blockDim.x + threadIdx.x;
  if (e < N_EDGES) {
    int pos = atomicAdd(&cursor[tgt[e]], 1);
    adj[pos] = src[e];
  }
}

// ---------------- register-tiled GEMM: g[n][f] = dinv[n]*(A@W)[n][f] ----------------
// block: 256 threads -> 64 nodes x 96 feats output tile; thread: 4x6 register tile
template<int K>
__global__ __launch_bounds__(256) void k_gemm_tile(
    const float* __restrict__ A, const float* __restrict__ W,
    const float* __restrict__ dinv, float* __restrict__ g) {
  constexpr int BM = 64, KB = 32;
  __shared__ float As[KB][BM + 4];   // k-major (transposed), pad keeps float4 align + spreads banks
  __shared__ float Ws[KB][HID];
  int tid = threadIdx.x;
  int tx = tid & 15;         // f0 = tx*6
  int ty = tid >> 4;         // n-off = ty*4
  int f0 = tx * 6;
  int nbase = blockIdx.x * BM;
  float acc[4][6] = {};

  for (int k0 = 0; k0 < K; k0 += KB) {
    // stage A tile (64 x 32), transposed into As
#pragma unroll
    for (int i = 0; i < 2; i++) {
      int l = tid + i * 256;           // 0..511
      int row = l >> 3;                // 0..63
      int col = (l & 7) * 4;           // 0,4,..28
      int n = nbase + row;
      float4 a4 = make_float4(0.f, 0.f, 0.f, 0.f);
      if (n < N_NODES) a4 = *reinterpret_cast<const float4*>(A + (size_t)n * K + k0 + col);
      As[col + 0][row] = a4.x;
      As[col + 1][row] = a4.y;
      As[col + 2][row] = a4.z;
      As[col + 3][row] = a4.w;
    }
    // stage W tile (32 x 96), direct copy
#pragma unroll
    for (int i = 0; i < 3; i++) {
      int l = tid + i * 256;           // 0..767
      int row = l / 24;                // 0..31
      int col = (l % 24) * 4;          // 0..92
      *reinterpret_cast<float4*>(&Ws[row][col]) =
          *reinterpret_cast<const float4*>(W + (size_t)(k0 + row) * HID + col);
    }
    __syncthreads();
#pragma unroll
    for (int k = 0; k < KB; k++) {
      float4 a4 = *reinterpret_cast<const float4*>(&As[k][ty * 4]);
      float2 w01 = *reinterpret_cast<const float2*>(&Ws[k][f0]);
      float2 w23 = *reinterpret_cast<const float2*>(&Ws[k][f0 + 2]);
      float2 w45 = *reinterpret_cast<const float2*>(&Ws[k][f0 + 4]);
      float av[4] = {a4.x, a4.y, a4.z, a4.w};
      float wv[6] = {w01.x, w01.y, w23.x, w23.y, w45.x, w45.y};
#pragma unroll
      for (int i = 0; i < 4; i++)
#pragma unroll
        for (int j = 0; j < 6; j++) acc[i][j] += av[i] * wv[j];
    }
    __syncthreads();
  }

#pragma unroll
  for (int i = 0; i < 4; i++) {
    int n = nbase + ty * 4 + i;
    if (n >= N_NODES) break;
    float d = dinv[n];
    float* gp = g + (size_t)n * HID + f0;
#pragma unroll
    for (int j = 0; j < 6; j++) gp[j] = acc[i][j] * d;
  }
}

// ---------------- fused aggregate: h = leaky(dinv*(g[n] + sum_in g[src]) + b) ----------------
__global__ __launch_bounds__(256) void k_aggregate(
    const float* __restrict__ g, const int* __restrict__ rowptr,
    const int* __restrict__ adj, const float* __restrict__ dinv,
    const float* __restrict__ b, float* __restrict__ h) {
  int wave = threadIdx.x >> 6;
  int lane = threadIdx.x & 63;
  int n = blockIdx.x * 4 + wave;
  if (n >= N_NODES) return;
  const float* grow = g + (size_t)n * HID;
  float s0 = grow[lane];
  float s1 = (lane < 32) ? grow[64 + lane] : 0.f;
  int beg = rowptr[n], end = rowptr[n + 1];
  for (int e = beg; e < end; e++) {
    int src = adj[e];
    const float* gs = g + (size_t)src * HID;
    s0 += gs[lane];
    if (lane < 32) s1 += gs[64 + lane];
  }
  float d = dinv[n];
  float v0 = d * s0 + b[lane];
  h[(size_t)n * HID + lane] = v0 > 0.f ? v0 : 0.01f * v0;
  if (lane < 32) {
    float v1 = d * s1 + b[64 + lane];
    h[(size_t)n * HID + 64 + lane] = v1 > 0.f ? v1 : 0.01f * v1;
  }
}

// ---------------- final linear: out = H @ Wl + bl ----------------
__global__ __launch_bounds__(256) void k_final(
    const float* __restrict__ H, const float* __restrict__ Wl,
    const float* __restrict__ bl, float* __restrict__ out) {
  __shared__ float w[HID * NCLS];
  __shared__ float bs[NCLS];
  int tid = threadIdx.x;
  for (int i = tid; i < HID * NCLS; i += 256) w[i] = Wl[i];
  if (tid < NCLS) bs[tid] = bl[tid];
  __syncthreads();
  int idx = blockIdx.x * 256 + tid;
  if (idx >= N_NODES * NCLS) return;
  int n = idx / NCLS;
  int c = idx - n * NCLS;
  const float* a = H + (size_t)n * HID;
  float s = bs[c];
#pragma unroll
  for (int k = 0; k < HID; k++) s += a[k] * w[k * NCLS + c];
  out[idx] = s;
}

extern "C" void kernel_launch(void* const* d_in, const int* in_sizes, int n_in,
                              void* d_out, int out_size, void* d_ws, size_t ws_size,
                              hipStream_t stream) {
  const float* x  = (const float*)d_in[0];
  const int* ei   = (const int*)d_in[1];
  const int* src  = ei;             // edge_index[0]
  const int* tgt  = ei + N_EDGES;   // edge_index[1]
  const float* W1 = (const float*)d_in[2];
  const float* b1 = (const float*)d_in[3];
  const float* W2 = (const float*)d_in[4];
  const float* b2 = (const float*)d_in[5];
  const float* W3 = (const float*)d_in[6];
  const float* b3 = (const float*)d_in[7];
  const float* Wl = (const float*)d_in[8];
  const float* bl = (const float*)d_in[9];
  float* out = (float*)d_out;

  // workspace layout
  float* dinv   = (float*)d_ws;                          // N
  float* bufA   = dinv + N_NODES;                        // N*96
  float* bufB   = bufA + (size_t)N_NODES * HID;          // N*96
  int*   cnt    = (int*)(bufB + (size_t)N_NODES * HID);  // N
  int*   rowptr = cnt + N_NODES;                         // N+1
  int*   cursor = rowptr + N_NODES + 1;                  // N
  int*   adj    = cursor + N_NODES;                      // E

  // ---- CSR build (also yields degrees -> dinv) ----
  k_zero_int<<<(N_NODES + 255) / 256, 256, 0, stream>>>(cnt, N_NODES);
  k_hist<<<(N_EDGES + 255) / 256, 256, 0, stream>>>(tgt, cnt);
  k_scan<<<1, 1024, 0, stream>>>(cnt, rowptr);
  k_dinv_from_cnt<<<(N_NODES + 255) / 256, 256, 0, stream>>>(cnt, dinv);
  k_copy_int<<<(N_NODES + 255) / 256, 256, 0, stream>>>(rowptr, cursor, N_NODES);
  k_fill<<<(N_EDGES + 255) / 256, 256, 0, stream>>>(src, tgt, cursor, adj);

  const int ggrid = (N_NODES + 63) / 64;
  const int agrid = (N_NODES + 3) / 4;

  // ---- layer 1 ----
  k_gemm_tile<IN_F><<<ggrid, 256, 0, stream>>>(x, W1, dinv, bufA);
  k_aggregate<<<agrid, 256, 0, stream>>>(bufA, rowptr, adj, dinv, b1, bufB);
  // ---- layer 2 ----
  k_gemm_tile<HID><<<ggrid, 256, 0, stream>>>(bufB, W2, dinv, bufA);
  k_aggregate<<<agrid, 256, 0, stream>>>(bufA, rowptr, adj, dinv, b2, bufB);
  // ---- layer 3 ----
  k_gemm_tile<HID><<<ggrid, 256, 0, stream>>>(bufB, W3, dinv, bufA);
  k_aggregate<<<agrid, 256, 0, stream>>>(bufA, rowptr, adj, dinv, b3, bufB);

  // ---- classifier ----
  k_final<<<(N_NODES * NCLS + 255) / 256, 256, 0, stream>>>(bufB, Wl, bl, out);
}

// Round 4
// 358.515 us; speedup vs baseline: 3.4260x; 1.3935x over previous
//
#include <hip/hip_runtime.h>

#define N_NODES 50000
#define N_EDGES 800000
#define IN_F 128
#define HID 96
#define NCLS 21
#define NBLK ((N_NODES + 255) / 256)

// ---------------- CSR build ----------------
__global__ void k_zero_int(int* __restrict__ p, int n) {
  int i = blockIdx.x * blockDim.x + threadIdx.x;
  if (i < n) p[i] = 0;
}

__global__ void k_hist(const int* __restrict__ tgt, int* __restrict__ cnt) {
  int e = blockIdx.x * blockDim.x + threadIdx.x;
  if (e < N_EDGES) atomicAdd(&cnt[tgt[e]], 1);
}

// block-level exclusive prescan: pre[i] = exclusive scan within block, bsum[b] = block total
__global__ __launch_bounds__(256) void k_scan1(const int* __restrict__ cnt,
                                               int* __restrict__ pre,
                                               int* __restrict__ bsum) {
  __shared__ int ws[4];
  int tid = threadIdx.x;
  int i = blockIdx.x * 256 + tid;
  int lane = tid & 63, wid = tid >> 6;
  int v = (i < N_NODES) ? cnt[i] : 0;
  int x = v;
#pragma unroll
  for (int off = 1; off < 64; off <<= 1) {
    int y = __shfl_up(x, off);
    if (lane >= off) x += y;
  }
  if (lane == 63) ws[wid] = x;
  __syncthreads();
  if (tid == 0) {
    int t0 = ws[0], t1 = ws[1], t2 = ws[2], t3 = ws[3];
    ws[0] = 0; ws[1] = t0; ws[2] = t0 + t1; ws[3] = t0 + t1 + t2;
    bsum[blockIdx.x] = t0 + t1 + t2 + t3;
  }
  __syncthreads();
  if (i < N_NODES) pre[i] = ws[wid] + x - v;
}

// exclusive scan of the NBLK block sums, in place (NBLK <= 256), single block
__global__ __launch_bounds__(256) void k_scan2(int* __restrict__ bsum) {
  __shared__ int ws[4];
  int tid = threadIdx.x;
  int lane = tid & 63, wid = tid >> 6;
  int v = (tid < NBLK) ? bsum[tid] : 0;
  int x = v;
#pragma unroll
  for (int off = 1; off < 64; off <<= 1) {
    int y = __shfl_up(x, off);
    if (lane >= off) x += y;
  }
  if (lane == 63) ws[wid] = x;
  __syncthreads();
  if (tid == 0) {
    int t0 = ws[0], t1 = ws[1], t2 = ws[2];
    ws[3] = t0 + t1 + t2; ws[2] = t0 + t1; ws[1] = t0; ws[0] = 0;
  }
  __syncthreads();
  if (tid < NBLK) bsum[tid] = ws[wid] + x - v;
}

// finalize: rowptr/cursor/dinv in one pass; rowptr[N] is the known edge count
__global__ __launch_bounds__(256) void k_finalize(
    const int* __restrict__ cnt, const int* __restrict__ pre,
    const int* __restrict__ bsum, int* __restrict__ rowptr,
    int* __restrict__ cursor, float* __restrict__ dinv) {
  int i = blockIdx.x * 256 + threadIdx.x;
  if (i >= N_NODES) return;
  int r = pre[i] + bsum[blockIdx.x];
  rowptr[i] = r;
  cursor[i] = r;
  dinv[i] = rsqrtf(1.0f + (float)cnt[i]);  // +1 self-loop
  if (i == 0) rowptr[N_NODES] = N_EDGES;
}

__global__ void k_fill(const int* __restrict__ src, const int* __restrict__ tgt,
                       int* __restrict__ cursor, int* __restrict__ adj) {
  int e = blockIdx.x * blockDim.x + threadIdx.x;
  if (e < N_EDGES) {
    int pos = atomicAdd(&cursor[tgt[e]], 1);
    adj[pos] = src[e];
  }
}

// ---------------- register-tiled GEMM: g[n][f] = dinv[n]*(A@W)[n][f] ----------------
template<int K>
__global__ __launch_bounds__(256) void k_gemm_tile(
    const float* __restrict__ A, const float* __restrict__ W,
    const float* __restrict__ dinv, float* __restrict__ g) {
  constexpr int BM = 64, KB = 32;
  __shared__ float As[KB][BM + 4];
  __shared__ float Ws[KB][HID];
  int tid = threadIdx.x;
  int tx = tid & 15;
  int ty = tid >> 4;
  int f0 = tx * 6;
  int nbase = blockIdx.x * BM;
  float acc[4][6] = {};

  for (int k0 = 0; k0 < K; k0 += KB) {
#pragma unroll
    for (int i = 0; i < 2; i++) {
      int l = tid + i * 256;
      int row = l >> 3;
      int col = (l & 7) * 4;
      int n = nbase + row;
      float4 a4 = make_float4(0.f, 0.f, 0.f, 0.f);
      if (n < N_NODES) a4 = *reinterpret_cast<const float4*>(A + (size_t)n * K + k0 + col);
      As[col + 0][row] = a4.x;
      As[col + 1][row] = a4.y;
      As[col + 2][row] = a4.z;
      As[col + 3][row] = a4.w;
    }
#pragma unroll
    for (int i = 0; i < 3; i++) {
      int l = tid + i * 256;
      int row = l / 24;
      int col = (l % 24) * 4;
      *reinterpret_cast<float4*>(&Ws[row][col]) =
          *reinterpret_cast<const float4*>(W + (size_t)(k0 + row) * HID + col);
    }
    __syncthreads();
#pragma unroll
    for (int k = 0; k < KB; k++) {
      float4 a4 = *reinterpret_cast<const float4*>(&As[k][ty * 4]);
      float2 w01 = *reinterpret_cast<const float2*>(&Ws[k][f0]);
      float2 w23 = *reinterpret_cast<const float2*>(&Ws[k][f0 + 2]);
      float2 w45 = *reinterpret_cast<const float2*>(&Ws[k][f0 + 4]);
      float av[4] = {a4.x, a4.y, a4.z, a4.w};
      float wv[6] = {w01.x, w01.y, w23.x, w23.y, w45.x, w45.y};
#pragma unroll
      for (int i = 0; i < 4; i++)
#pragma unroll
        for (int j = 0; j < 6; j++) acc[i][j] += av[i] * wv[j];
    }
    __syncthreads();
  }

#pragma unroll
  for (int i = 0; i < 4; i++) {
    int n = nbase + ty * 4 + i;
    if (n >= N_NODES) break;
    float d = dinv[n];
    float* gp = g + (size_t)n * HID + f0;
#pragma unroll
    for (int j = 0; j < 6; j++) gp[j] = acc[i][j] * d;
  }
}

// ---------------- fused aggregate, 4-wide MLP unroll ----------------
__global__ __launch_bounds__(256) void k_aggregate(
    const float* __restrict__ g, const int* __restrict__ rowptr,
    const int* __restrict__ adj, const float* __restrict__ dinv,
    const float* __restrict__ b, float* __restrict__ h) {
  int wave = threadIdx.x >> 6;
  int lane = threadIdx.x & 63;
  int n = blockIdx.x * 4 + wave;
  if (n >= N_NODES) return;
  bool lo = lane < 32;
  const float* grow = g + (size_t)n * HID;
  float s0 = grow[lane];
  float s1 = lo ? grow[64 + lane] : 0.f;
  int beg = rowptr[n], end = rowptr[n + 1];
  int e = beg;
  for (; e + 4 <= end; e += 4) {
    int i0 = adj[e], i1 = adj[e + 1], i2 = adj[e + 2], i3 = adj[e + 3];
    const float* p0 = g + (size_t)i0 * HID;
    const float* p1 = g + (size_t)i1 * HID;
    const float* p2 = g + (size_t)i2 * HID;
    const float* p3 = g + (size_t)i3 * HID;
    float a0 = p0[lane], a1 = p1[lane], a2 = p2[lane], a3 = p3[lane];
    float c0 = 0.f, c1 = 0.f, c2 = 0.f, c3 = 0.f;
    if (lo) {
      c0 = p0[64 + lane]; c1 = p1[64 + lane];
      c2 = p2[64 + lane]; c3 = p3[64 + lane];
    }
    s0 += (a0 + a1) + (a2 + a3);
    s1 += (c0 + c1) + (c2 + c3);
  }
  for (; e < end; e++) {
    const float* p = g + (size_t)adj[e] * HID;
    s0 += p[lane];
    if (lo) s1 += p[64 + lane];
  }
  float d = dinv[n];
  float v0 = d * s0 + b[lane];
  h[(size_t)n * HID + lane] = v0 > 0.f ? v0 : 0.01f * v0;
  if (lo) {
    float v1 = d * s1 + b[64 + lane];
    h[(size_t)n * HID + 64 + lane] = v1 > 0.f ? v1 : 0.01f * v1;
  }
}

// ---------------- final linear: out = H @ Wl + bl ----------------
__global__ __launch_bounds__(256) void k_final(
    const float* __restrict__ H, const float* __restrict__ Wl,
    const float* __restrict__ bl, float* __restrict__ out) {
  __shared__ float w[HID * NCLS];
  __shared__ float bs[NCLS];
  int tid = threadIdx.x;
  for (int i = tid; i < HID * NCLS; i += 256) w[i] = Wl[i];
  if (tid < NCLS) bs[tid] = bl[tid];
  __syncthreads();
  int idx = blockIdx.x * 256 + tid;
  if (idx >= N_NODES * NCLS) return;
  int n = idx / NCLS;
  int c = idx - n * NCLS;
  const float* a = H + (size_t)n * HID;
  float s = bs[c];
#pragma unroll
  for (int k = 0; k < HID; k++) s += a[k] * w[k * NCLS + c];
  out[idx] = s;
}

extern "C" void kernel_launch(void* const* d_in, const int* in_sizes, int n_in,
                              void* d_out, int out_size, void* d_ws, size_t ws_size,
                              hipStream_t stream) {
  const float* x  = (const float*)d_in[0];
  const int* ei   = (const int*)d_in[1];
  const int* src  = ei;             // edge_index[0]
  const int* tgt  = ei + N_EDGES;   // edge_index[1]
  const float* W1 = (const float*)d_in[2];
  const float* b1 = (const float*)d_in[3];
  const float* W2 = (const float*)d_in[4];
  const float* b2 = (const float*)d_in[5];
  const float* W3 = (const float*)d_in[6];
  const float* b3 = (const float*)d_in[7];
  const float* Wl = (const float*)d_in[8];
  const float* bl = (const float*)d_in[9];
  float* out = (float*)d_out;

  // workspace layout
  float* dinv   = (float*)d_ws;                          // N
  float* bufA   = dinv + N_NODES;                        // N*96
  float* bufB   = bufA + (size_t)N_NODES * HID;          // N*96
  int*   cnt    = (int*)(bufB + (size_t)N_NODES * HID);  // N
  int*   rowptr = cnt + N_NODES;                         // N+1
  int*   cursor = rowptr + N_NODES + 1;                  // N
  int*   adj    = cursor + N_NODES;                      // E
  int*   pre    = adj + N_EDGES;                         // N
  int*   bsum   = pre + N_NODES;                         // NBLK

  // ---- CSR build (also yields degrees -> dinv) ----
  k_zero_int<<<NBLK, 256, 0, stream>>>(cnt, N_NODES);
  k_hist<<<(N_EDGES + 255) / 256, 256, 0, stream>>>(tgt, cnt);
  k_scan1<<<NBLK, 256, 0, stream>>>(cnt, pre, bsum);
  k_scan2<<<1, 256, 0, stream>>>(bsum);
  k_finalize<<<NBLK, 256, 0, stream>>>(cnt, pre, bsum, rowptr, cursor, dinv);
  k_fill<<<(N_EDGES + 255) / 256, 256, 0, stream>>>(src, tgt, cursor, adj);

  const int ggrid = (N_NODES + 63) / 64;
  const int agrid = (N_NODES + 3) / 4;

  // ---- layer 1 ----
  k_gemm_tile<IN_F><<<ggrid, 256, 0, stream>>>(x, W1, dinv, bufA);
  k_aggregate<<<agrid, 256, 0, stream>>>(bufA, rowptr, adj, dinv, b1, bufB);
  // ---- layer 2 ----
  k_gemm_tile<HID><<<ggrid, 256, 0, stream>>>(bufB, W2, dinv, bufA);
  k_aggregate<<<agrid, 256, 0, stream>>>(bufA, rowptr, adj, dinv, b2, bufB);
  // ---- layer 3 ----
  k_gemm_tile<HID><<<ggrid, 256, 0, stream>>>(bufB, W3, dinv, bufA);
  k_aggregate<<<agrid, 256, 0, stream>>>(bufA, rowptr, adj, dinv, b3, bufB);

  // ---- classifier ----
  k_final<<<(N_NODES * NCLS + 255) / 256, 256, 0, stream>>>(bufB, Wl, bl, out);
}